// Round 12
// baseline (196.300 us; speedup 1.0000x reference)
//
#include <hip/hip_runtime.h>

typedef unsigned short u16;
typedef unsigned int u32;
typedef __attribute__((ext_vector_type(8))) short bf16x8;
typedef __attribute__((ext_vector_type(4))) float f32x4;

__device__ __forceinline__ u16 f2bf(float f) {
    u32 u = __float_as_uint(f);
    u += 0x7fffu + ((u >> 16) & 1u);
    return (u16)(u >> 16);
}

// pack two f32 -> one u32 of two bf16 (RNE), 1 VALU inst
__device__ __forceinline__ u32 cvtpk(float lo, float hi) {
    u32 r;
    asm("v_cvt_pk_bf16_f32 %0, %1, %2" : "=v"(r) : "v"(lo), "v"(hi));
    return r;
}

// async global->LDS DMA, 16B per lane, LDS dest = wave-uniform base (+lane*16 by HW)
#define GL2LDS(gp, lp)                                                                 \
    __builtin_amdgcn_global_load_lds((const __attribute__((address_space(1))) u32*)(const void*)(gp), \
                                     (__attribute__((address_space(3))) u32*)(void*)(lp), 16, 0, 0)

#define SBAR                                                                           \
    do {                                                                               \
        __builtin_amdgcn_sched_barrier(0);                                             \
        __builtin_amdgcn_s_barrier();                                                  \
        __builtin_amdgcn_sched_barrier(0);                                             \
    } while (0)
#define WAITV(N)                                                                       \
    do {                                                                               \
        asm volatile("s_waitcnt vmcnt(" #N ")" ::: "memory");                          \
        __builtin_amdgcn_sched_barrier(0);                                             \
    } while (0)
#define WAITLGKM0                                                                      \
    do {                                                                               \
        asm volatile("s_waitcnt lgkmcnt(0)" ::: "memory");                             \
        __builtin_amdgcn_sched_barrier(0);                                             \
    } while (0)

// ------------- fused prep: cast x (bid<4096) | transpose W (bid<8192) | rtab -------------
__global__ __launch_bounds__(256) void prep_kernel(const float* __restrict__ x,
                                                   const float* __restrict__ Wq,
                                                   const float* __restrict__ Wk,
                                                   const float* __restrict__ Wv,
                                                   const float* __restrict__ Wo,
                                                   const float* __restrict__ wp,
                                                   const float* __restrict__ vp,
                                                   u16* __restrict__ xb,
                                                   u16* __restrict__ Wcat,
                                                   u16* __restrict__ Wot,
                                                   float* __restrict__ tab,
                                                   u32* __restrict__ counter) {
    __shared__ float tl[32][33];
    const int bid = blockIdx.x, t = threadIdx.x;
    if (bid < 4096) {  // ---- cast x fp32 -> bf16, float4/thread ----
        const int i = bid * 256 + t;
        float4 val = ((const float4*)x)[i];
        uint2 o;
        o.x = cvtpk(val.x, val.y);
        o.y = cvtpk(val.z, val.w);
        ((uint2*)xb)[i] = o;
    } else if (bid < 8192) {  // ---- transpose+cast one 32x32 tile of Wq/Wk/Wv/Wo ----
        const int tid = bid - 4096;
        const int zi = tid >> 10, rem = tid & 1023;
        const int kt = (rem >> 5) * 32, nt = (rem & 31) * 32;
        const float* src = (zi == 0) ? Wq : (zi == 1) ? Wk : (zi == 2) ? Wv : Wo;
        u16* dst = (zi < 3) ? (Wcat + zi * 1048576) : Wot;
        const int tx = t & 31, ty = t >> 5;
#pragma unroll
        for (int j = 0; j < 4; ++j)
            tl[ty + j * 8][tx] = src[(kt + ty + j * 8) * 1024 + nt + tx];
        __syncthreads();
#pragma unroll
        for (int j = 0; j < 4; ++j)
            dst[(nt + ty + j * 8) * 1024 + kt + tx] = f2bf(tl[tx][ty + j * 8]);
    } else {  // ---- R_hat table: (1+e^v)/(1+e^(v-w*d))/8 * log2e (exp2-baked) ----
        const int i = (bid - 8192) * 256 + t;  // 16*2048
        if (i == 0) counter[0] = 0u;           // work-stealing counter for attn
        const int h = i >> 11, d = i & 2047;
        const float vv = vp[h], ww = wp[h];
        tab[i] = (1.f + expf(vv)) / (1.f + expf(vv - ww * (float)d)) *
                 (0.125f * 1.44269504088896340736f);
    }
}

// ---------------- 8-phase 256x256 QKV GEMM (T2+T3+T4+T5 template) ----------------
// C = A[4096][1024] @ Bt[3072][1024]^T.  512 thr = 8 waves (2M x 4N); per-wave out
// 128x64.  LDS 128KB dynamic: per operand 2 dbuf x 2 K-half units, unit=[256][32] bf16
// (16KB, one GL2LDS stage: 2 loads/thread).  Swizzle chunk^=(row&3) on read + inverse
// on global source (both-sides rule).  Phase (mh,kh): 8 ds_read_b128 -> stage 1 unit
// -> barrier -> lgkm0 -> setprio+16 MFMA -> [vmcnt(8) at even phases] -> barrier.
// Stage targets freed >=1 barrier earlier (audited); vmcnt(8) leaves 4 units (~4
// phases) in flight, never drains.  Tail iter waits 8/4/0.  Epilogue = proven MODE1
// stores (Q|K row-major; V^T permuted for attn's single-b128 PV frags).
__global__ __launch_bounds__(512, 2) void gemm256(const u16* __restrict__ A,
                                                  const u16* __restrict__ Bt,
                                                  u16* __restrict__ Cb,
                                                  u16* __restrict__ Vt) {
    extern __shared__ u16 sm[];  // [A|B][2 dbuf][2 kh][256][32] u16 = 128 KB
    const int t = threadIdx.x, lane = t & 63, w = t >> 6;  // 8 waves
    const int l15 = lane & 15, quad = lane >> 4;
    const int wr = w >> 2, wc = w & 3;
    const int m0 = blockIdx.y << 8, n0 = blockIdx.x << 8;
    const int srow = lane >> 2, sc = lane & 3;  // staging: 4 lanes/row, chunk 0..3

    f32x4 acc[8][4];
#pragma unroll
    for (int i = 0; i < 8; ++i)
#pragma unroll
        for (int j = 0; j < 4; ++j) acc[i][j] = (f32x4){0.f, 0.f, 0.f, 0.f};

    // stage unit (operand O, K-tile kt, half kh) -> dbuf kt&1.  2 GL2LDS/thread.
    auto stage = [&](int O, int kt, int kh) {
        const u16* src = O ? Bt : A;
        const int g0 = O ? n0 : m0;
        const int base = O * 32768 + (kt & 1) * 16384 + kh * 8192;
        const int k0 = (kt << 6) + (kh << 5);
#pragma unroll
        for (int j = 0; j < 2; ++j) {
            const int row = (w * 2 + j) * 16 + srow;
            const int g = (sc ^ (row & 3)) << 3;  // inverse swizzle on source
            GL2LDS(src + (size_t)(g0 + row) * 1024 + k0 + g,
                   &sm[base + (w * 2 + j) * 512]);
        }
    };

    // one phase: quadrant (mh,kh) of tile in dbuf d; stg = stage op; wmode wait
    auto phase = [&](int d, int mh, int kh, auto&& stg, int wmode) {
        bf16x8 af[4], bf[4];
        const int ab = d * 16384 + kh * 8192;
        const int bb = 32768 + d * 16384 + kh * 8192;
#pragma unroll
        for (int mm = 0; mm < 4; ++mm) {
            const int row = wr * 128 + mh * 64 + mm * 16 + l15;
            af[mm] = *(const bf16x8*)&sm[ab + row * 32 + ((quad ^ (row & 3)) << 3)];
        }
#pragma unroll
        for (int nn = 0; nn < 4; ++nn) {
            const int row = wc * 64 + nn * 16 + l15;
            bf[nn] = *(const bf16x8*)&sm[bb + row * 32 + ((quad ^ (row & 3)) << 3)];
        }
        stg();
        SBAR;
        WAITLGKM0;
        __builtin_amdgcn_s_setprio(1);
#pragma unroll
        for (int mm = 0; mm < 4; ++mm)
#pragma unroll
            for (int nn = 0; nn < 4; ++nn)
                acc[mh * 4 + mm][nn] = __builtin_amdgcn_mfma_f32_16x16x32_bf16(
                    af[mm], bf[nn], acc[mh * 4 + mm][nn], 0, 0, 0);
        __builtin_amdgcn_s_setprio(0);
        if (wmode == 1) WAITV(8);
        else if (wmode == 2) WAITV(4);
        else if (wmode == 3) WAITV(0);
        SBAR;
    };

    // prologue: tile0 (4 units) + tile1 kh0 (2 units), in retirement order
    stage(0, 0, 0); stage(1, 0, 0); stage(0, 0, 1); stage(1, 0, 1);
    stage(0, 1, 0); stage(1, 1, 0);
    WAITV(8);  // retires tile0 kh0+kh1 (oldest 4 loads... oldest 4 = A00,B00; 8 left)
    SBAR;      // collective: all waves' tile0-kh0 portions landed

    for (int i = 0; i < 8; ++i) {  // tiles 2i (dbuf0), 2i+1 (dbuf1); 16 K-tiles total
        const bool nl = (i < 7);
        phase(0, 0, 0, [&] { stage(0, 2 * i + 1, 1); }, 0);            // ph1
        phase(0, 1, 0, [&] { stage(1, 2 * i + 1, 1); }, 1);            // ph2 vmcnt(8)
        phase(0, 0, 1, [&] { if (nl) stage(0, 2 * i + 2, 0); }, 0);    // ph3
        phase(0, 1, 1, [&] { if (nl) stage(1, 2 * i + 2, 0); }, nl ? 1 : 2);  // ph4
        phase(1, 0, 0, [&] { if (nl) stage(0, 2 * i + 2, 1); }, 0);    // ph5
        phase(1, 1, 0, [&] { if (nl) stage(1, 2 * i + 2, 1); }, nl ? 1 : 3);  // ph6
        phase(1, 0, 1, [&] { if (nl) stage(0, 2 * i + 3, 0); }, 0);    // ph7
        phase(1, 1, 1, [&] { if (nl) stage(1, 2 * i + 3, 0); }, nl ? 1 : 0);  // ph8
    }

    // epilogue: C/D layout col=lane&15, row=(lane>>4)*4+reg (same as gemm128)
    const int cb0 = n0 + wc * 64;
#pragma unroll
    for (int am = 0; am < 8; ++am) {
#pragma unroll
        for (int nn = 0; nn < 4; ++nn) {
            const int col = cb0 + nn * 16 + l15;
            if (n0 < 2048) {  // Q|K: row-major bf16 [M][2048]
                const int row = m0 + wr * 128 + am * 16 + (quad << 2);
#pragma unroll
                for (int r = 0; r < 4; ++r)
                    Cb[(size_t)(row + r) * 2048 + col] = f2bf(acc[am][nn][r]);
            } else {  // V: permuted V^T store (64-row window, proven pos formula)
                const int mm = am & 3, mh = am >> 2;
                const int win = m0 + wr * 128 + mh * 64;
                const int pos = (((mm >> 1) * 4 + quad) << 3) + ((mm & 1) << 2);
                uint2 o;
                o.x = cvtpk(acc[am][nn][0], acc[am][nn][1]);
                o.y = cvtpk(acc[am][nn][2], acc[am][nn][3]);
                *(uint2*)(Vt + (size_t)(col - 2048) * 4096 + win + pos) = o;
            }
        }
    }
}

// ---------------- m97-style bf16 MFMA GEMM (out-proj): 128x64 tile, MODE0 ----------------
template <int MODE, int BN>
__global__ __launch_bounds__(256, 3) void gemm128(const u16* __restrict__ A,
                                                  const u16* __restrict__ Bt,
                                                  float* __restrict__ C,
                                                  const float* __restrict__ bias,
                                                  int M, int N, int K) {
    constexpr int NBW = BN / 32;
    __shared__ __align__(16) u16 As[8192];
    __shared__ __align__(16) u16 Bs[BN * 64];
    const int t = threadIdx.x, lane = t & 63, wv = t >> 6;
    const int l15 = lane & 15, quad = lane >> 4;
    const int m0 = blockIdx.y << 7, n0 = blockIdx.x * BN;
    const int wm = (wv & 1) << 6, wn = (wv >> 1) * (BN / 2);

    f32x4 acc[4][NBW];
#pragma unroll
    for (int i = 0; i < 4; ++i)
#pragma unroll
        for (int j = 0; j < NBW; ++j) acc[i][j] = (f32x4){0.f, 0.f, 0.f, 0.f};

    const int lrow = lane >> 3, lchunk = lane & 7;
    for (int k0 = 0; k0 < K; k0 += 64) {
#pragma unroll
        for (int c = 0; c < 4; ++c) {
            const int r0 = wv * 32 + c * 8;
            const int row = r0 + lrow;
            const int g = lchunk ^ (row & 7);
            GL2LDS(A + (size_t)(m0 + row) * K + k0 + g * 8, &As[r0 * 64]);
        }
#pragma unroll
        for (int c = 0; c < BN / 32; ++c) {
            const int r0 = wv * (BN / 4) + c * 8;
            const int row = r0 + lrow;
            const int g = lchunk ^ (row & 7);
            GL2LDS(Bt + (size_t)(n0 + row) * K + k0 + g * 8, &Bs[r0 * 64]);
        }
        __syncthreads();
#pragma unroll
        for (int ks = 0; ks < 2; ++ks) {
            const int p = ((ks << 2) | quad) ^ (l15 & 7);
            bf16x8 af[4], bfr[NBW];
#pragma unroll
            for (int i = 0; i < 4; ++i)
                af[i] = *(const bf16x8*)&As[(wm + i * 16 + l15) * 64 + p * 8];
#pragma unroll
            for (int j = 0; j < NBW; ++j)
                bfr[j] = *(const bf16x8*)&Bs[(wn + j * 16 + l15) * 64 + p * 8];
#pragma unroll
            for (int mb = 0; mb < 4; ++mb)
#pragma unroll
                for (int nb = 0; nb < NBW; ++nb)
                    acc[mb][nb] = __builtin_amdgcn_mfma_f32_16x16x32_bf16(af[mb], bfr[nb],
                                                                          acc[mb][nb], 0, 0, 0);
        }
        __syncthreads();
    }
    const int rb = m0 + wm + (quad << 2);
    const int cbase = n0 + wn + l15;
#pragma unroll
    for (int mb = 0; mb < 4; ++mb)
#pragma unroll
        for (int nb = 0; nb < NBW; ++nb) {
            const int col = cbase + nb * 16;
#pragma unroll
            for (int r = 0; r < 4; ++r) {
                const int row = rb + mb * 16 + r;
                C[(size_t)row * N + col] = acc[mb][nb][r] + bias[col];
            }
        }
}

// ---------------- MFMA flash attention v13 (R10 best): counted-vmcnt deep pipeline ----
__global__ __launch_bounds__(256, 3) void attn_kernel(const u16* __restrict__ qkb,
                                                      const u16* __restrict__ vtb,
                                                      const float* __restrict__ rtab,
                                                      u16* __restrict__ ctxb,
                                                      u32* __restrict__ counter) {
    __shared__ __align__(16) u16 Kt[3][4096];   // [kseq][d] swizzled, 8KB x3
    __shared__ __align__(16) u16 Vt2[2][4096];  // [d][kseq-permuted] swizzled, 8KB x2
    __shared__ __align__(16) float rall[2048];  // R_hat*log2e/8 row for this head
    __shared__ int jobS;

    const int t = threadIdx.x, lane = t & 63, wv = t >> 6;
    const int l15 = lane & 15, quad = lane >> 4;
    const int lrow = lane >> 3, lchunk = lane & 7;
    const int half0 = (wv & 1) * 32;

    for (;;) {
        if (t == 0) jobS = (int)atomicAdd(counter, 1u);
        __syncthreads();
        const int job = jobS;
        if (job >= 1024) break;
        const int qt = 31 - (job >> 5);
        const int bh = job & 31;
        const int b = bh >> 4, h = bh & 15;
        const int q0 = qt << 6;

        {
            const float4* src = (const float4*)(rtab + (h << 11));
            const int nf = (q0 + 64) >> 2;
            for (int i = t; i < nf; i += 256) ((float4*)rall)[i] = src[i];
        }

        bf16x8 qb[2];
        {
            const u16* qrow = qkb + (size_t)(b * 2048 + q0 + (wv << 4) + l15) * 2048 +
                              (h << 6) + quad * 8;
            qb[0] = *(const bf16x8*)(qrow);
            qb[1] = *(const bf16x8*)(qrow + 32);
        }

        auto stage_k = [&](int ktile, int kb) {
#pragma unroll
            for (int c = 0; c < 4; ++c) {
                const int r0 = half0 + c * 8;
                const int row = r0 + lrow;
                const int g = lchunk ^ (row & 7);
                GL2LDS(qkb + (size_t)(b * 2048 + (ktile << 6) + row) * 2048 + 1024 +
                           (h << 6) + g * 8,
                       &Kt[kb][r0 * 64]);
            }
        };
        auto stage_v = [&](int ktile, int vb) {
#pragma unroll
            for (int c = 0; c < 4; ++c) {
                const int r0 = half0 + c * 8;
                const int row = r0 + lrow;
                const int g = lchunk ^ (row & 7);
                GL2LDS(vtb + (size_t)((h << 6) + row) * 4096 + b * 2048 + (ktile << 6) +
                           g * 8,
                       &Vt2[vb][r0 * 64]);
            }
        };

        f32x4 cacc[4];
#pragma unroll
        for (int i = 0; i < 4; ++i) cacc[i] = (f32x4){0.f, 0.f, 0.f, 0.f};
        f32x4 lacc4 = (f32x4){0.f, 0.f, 0.f, 0.f};

        if (wv < 2) {
            stage_k(0, 0);
            if (qt >= 1) stage_k(1, 1);
        } else {
            stage_v(0, 0);
        }
        WAITLGKM0;  // publish rall fill at b1

        for (int kt = 0; kt <= qt; ++kt) {
            const int kb = kt % 3, vb = kt & 1;
            if (wv < 2) {
                if (kt < qt) WAITV(4);
                else         WAITV(0);
            }
            SBAR;  // b1: Kt[kb] ready
            if (wv < 2) {
                if (kt + 2 <= qt) stage_k(kt + 2, (kt + 2) % 3);
            } else {
                if (kt + 1 <= qt) stage_v(kt + 1, (kt + 1) & 1);
            }

            f32x4 sacc[4];
#pragma unroll
            for (int i = 0; i < 4; ++i) sacc[i] = (f32x4){0.f, 0.f, 0.f, 0.f};
            __builtin_amdgcn_s_setprio(1);
#pragma unroll
            for (int ks = 0; ks < 2; ++ks) {
                const int p = ((ks << 2) | quad) ^ (l15 & 7);
#pragma unroll
                for (int mb = 0; mb < 4; ++mb) {
                    bf16x8 ka = *(const bf16x8*)&Kt[kb][(mb * 16 + l15) * 64 + p * 8];
                    sacc[mb] = __builtin_amdgcn_mfma_f32_16x16x32_bf16(ka, qb[ks],
                                                                       sacc[mb], 0, 0, 0);
                }
            }
            __builtin_amdgcn_s_setprio(0);

            const int D0 = q0 - (kt << 6) + (wv << 4) + l15;
            u32 pk[4][2];
            if (kt < qt) {
#pragma unroll
                for (int mb = 0; mb < 4; ++mb) {
                    float pe[4];
#pragma unroll
                    for (int r = 0; r < 4; ++r) {
                        const int dist = D0 - (mb * 16 + (quad << 2) + r);
                        pe[r] = exp2f(fmaxf(sacc[mb][r], 0.f) * rall[dist]);
                        lacc4[r] += pe[r];
                    }
                    pk[mb][0] = cvtpk(pe[0], pe[1]);
                    pk[mb][1] = cvtpk(pe[2], pe[3]);
                }
            } else {
#pragma unroll
                for (int mb = 0; mb < 4; ++mb) {
                    float pe[4];
#pragma unroll
                    for (int r = 0; r < 4; ++r) {
                        const int dist = D0 - (mb * 16 + (quad << 2) + r);
                        const int di = dist < 0 ? 0 : dist;
                        float p0 = exp2f(fmaxf(sacc[mb][r], 0.f) * rall[di]);
                        pe[r] = (dist < 0) ? 0.f : p0;
                        lacc4[r] += pe[r];
                    }
                    pk[mb][0] = cvtpk(pe[0], pe[1]);
                    pk[mb][1] = cvtpk(pe[2], pe[3]);
                }
            }

            if (wv >= 2) {
                if (kt < qt) WAITV(4);
                else         WAITV(0);
            }
            SBAR;  // b2: Vt2[vb] ready

            __builtin_amdgcn_s_setprio(1);
#pragma unroll
            for (int ks = 0; ks < 2; ++ks) {
                int4 pv = {(int)pk[2 * ks][0], (int)pk[2 * ks][1],
                           (int)pk[2 * ks + 1][0], (int)pk[2 * ks + 1][1]};
                bf16x8 pb = *(bf16x8*)&pv;
                const int g = (4 * ks + quad) ^ (l15 & 7);
#pragma unroll
                for (int db = 0; db < 4; ++db) {
                    bf16x8 vf = *(const bf16x8*)&Vt2[vb][(db * 16 + l15) * 64 + g * 8];
                    cacc[db] = __builtin_amdgcn_mfma_f32_16x16x32_bf16(vf, pb,
                                                                       cacc[db], 0, 0, 0);
                }
            }
            __builtin_amdgcn_s_setprio(0);
        }

        float lt = (lacc4[0] + lacc4[1]) + (lacc4[2] + lacc4[3]);
        lt += __shfl_xor(lt, 16, 64);
        lt += __shfl_xor(lt, 32, 64);
        const float inv = 1.f / lt;
        u16* op = ctxb + (size_t)(b * 2048 + q0 + (wv << 4) + l15) * 1024 +
                  (h << 6) + (quad << 2);
#pragma unroll
        for (int db = 0; db < 4; ++db) {
            uint2 o;
            o.x = cvtpk(cacc[db][0] * inv, cacc[db][1] * inv);
            o.y = cvtpk(cacc[db][2] * inv, cacc[db][3] * inv);
            *(uint2*)(op + db * 16) = o;
        }
    }
}

extern "C" void kernel_launch(void* const* d_in, const int* in_sizes, int n_in,
                              void* d_out, int out_size, void* d_ws, size_t ws_size,
                              hipStream_t stream) {
    const float* x  = (const float*)d_in[0];
    const float* Wq = (const float*)d_in[1];
    const float* Wk = (const float*)d_in[2];
    const float* Wv = (const float*)d_in[3];
    const float* Wo = (const float*)d_in[4];
    const float* bo = (const float*)d_in[5];
    const float* w  = (const float*)d_in[6];
    const float* v  = (const float*)d_in[7];
    float* out = (float*)d_out;

    char* w8 = (char*)d_ws;
    u16*  xb   = (u16*)(w8);                     //  8 MB : x bf16 [4096][1024]
    u16*  Wcat = (u16*)(w8 + (8u << 20));        //  6 MB : (Wq|Wk|Wv)^T bf16 [3072][1024]
    u16*  Wot  = (u16*)(w8 + (14u << 20));       //  2 MB : Wo^T bf16 [1024][1024]
    u16*  qkb  = (u16*)(w8 + (16u << 20));       // 16 MB : Q|K bf16 [4096][2048]
    u16*  vtb  = (u16*)(w8 + (32u << 20));       //  8 MB : V^T bf16 [1024][4096] (permuted)
    u16*  ctxb = (u16*)(w8 + (40u << 20));       //  8 MB : ctx bf16 [4096][1024]
    float* rtab = (float*)(w8 + (48u << 20));    // 128 KB: R_hat*log2e/8 [16][2048]
    u32*  counter = (u32*)(w8 + (48u << 20) + (1u << 17));  // 4 B : job counter

    static bool attrSet = false;
    if (!attrSet) {
        hipFuncSetAttribute(reinterpret_cast<const void*>(gemm256),
                            hipFuncAttributeMaxDynamicSharedMemorySize, 131072);
        attrSet = true;
    }

    // fused prep: cast (4096 blk) | weight transpose (4096 blk) | rtab+counter (128 blk)
    prep_kernel<<<8320, 256, 0, stream>>>(x, Wq, Wk, Wv, Wo, w, v, xb, Wcat, Wot, rtab,
                                          counter);
    // QKV fused projection, 8-phase 256x256 -> qkb (Q|K) + vtb (V^T permuted)
    gemm256<<<dim3(12, 16), 512, 131072, stream>>>(xb, Wcat, qkb, vtb);
    // MFMA flash attention: 768 persistent blocks (3/CU), work-stealing
    attn_kernel<<<768, 256, 0, stream>>>(qkb, vtb, rtab, ctxb, counter);
    // output projection + bias (fp32 out)   [M=4096, N=1024, K=1024], 128x64 tiles
    gemm128<0, 64><<<dim3(16, 32), 256, 0, stream>>>(ctxb, Wot, out, bo, 4096, 1024, 1024);
}

// Round 13
// 194.708 us; speedup vs baseline: 1.0082x; 1.0082x over previous
//
#include <hip/hip_runtime.h>

typedef unsigned short u16;
typedef unsigned int u32;
typedef __attribute__((ext_vector_type(8))) short bf16x8;
typedef __attribute__((ext_vector_type(4))) float f32x4;

__device__ __forceinline__ u16 f2bf(float f) {
    u32 u = __float_as_uint(f);
    u += 0x7fffu + ((u >> 16) & 1u);
    return (u16)(u >> 16);
}

// pack two f32 -> one u32 of two bf16 (RNE), 1 VALU inst
__device__ __forceinline__ u32 cvtpk(float lo, float hi) {
    u32 r;
    asm("v_cvt_pk_bf16_f32 %0, %1, %2" : "=v"(r) : "v"(lo), "v"(hi));
    return r;
}

// async global->LDS DMA, 16B per lane, LDS dest = wave-uniform base (+lane*16 by HW)
#define GL2LDS(gp, lp)                                                                 \
    __builtin_amdgcn_global_load_lds((const __attribute__((address_space(1))) u32*)(const void*)(gp), \
                                     (__attribute__((address_space(3))) u32*)(void*)(lp), 16, 0, 0)

#define SBAR                                                                           \
    do {                                                                               \
        __builtin_amdgcn_sched_barrier(0);                                             \
        __builtin_amdgcn_s_barrier();                                                  \
        __builtin_amdgcn_sched_barrier(0);                                             \
    } while (0)
#define WAITV(N)                                                                       \
    do {                                                                               \
        asm volatile("s_waitcnt vmcnt(" #N ")" ::: "memory");                          \
        __builtin_amdgcn_sched_barrier(0);                                             \
    } while (0)
#define WAITLGKM0                                                                      \
    do {                                                                               \
        asm volatile("s_waitcnt lgkmcnt(0)" ::: "memory");                             \
        __builtin_amdgcn_sched_barrier(0);                                             \
    } while (0)

// ------------- fused prep: cast x (bid<4096) | transpose W (bid<8192) | rtab -------------
__global__ __launch_bounds__(256) void prep_kernel(const float* __restrict__ x,
                                                   const float* __restrict__ Wq,
                                                   const float* __restrict__ Wk,
                                                   const float* __restrict__ Wv,
                                                   const float* __restrict__ Wo,
                                                   const float* __restrict__ wp,
                                                   const float* __restrict__ vp,
                                                   u16* __restrict__ xb,
                                                   u16* __restrict__ Wcat,
                                                   u16* __restrict__ Wot,
                                                   float* __restrict__ tab,
                                                   u32* __restrict__ counter) {
    __shared__ float tl[32][33];
    const int bid = blockIdx.x, t = threadIdx.x;
    if (bid < 4096) {  // ---- cast x fp32 -> bf16, float4/thread ----
        const int i = bid * 256 + t;
        float4 val = ((const float4*)x)[i];
        uint2 o;
        o.x = cvtpk(val.x, val.y);
        o.y = cvtpk(val.z, val.w);
        ((uint2*)xb)[i] = o;
    } else if (bid < 8192) {  // ---- transpose+cast one 32x32 tile of Wq/Wk/Wv/Wo ----
        const int tid = bid - 4096;
        const int zi = tid >> 10, rem = tid & 1023;
        const int kt = (rem >> 5) * 32, nt = (rem & 31) * 32;
        const float* src = (zi == 0) ? Wq : (zi == 1) ? Wk : (zi == 2) ? Wv : Wo;
        u16* dst = (zi < 3) ? (Wcat + zi * 1048576) : Wot;
        const int tx = t & 31, ty = t >> 5;
#pragma unroll
        for (int j = 0; j < 4; ++j)
            tl[ty + j * 8][tx] = src[(kt + ty + j * 8) * 1024 + nt + tx];
        __syncthreads();
#pragma unroll
        for (int j = 0; j < 4; ++j)
            dst[(nt + ty + j * 8) * 1024 + kt + tx] = f2bf(tl[tx][ty + j * 8]);
    } else {  // ---- R_hat table: (1+e^v)/(1+e^(v-w*d))/8 * log2e (exp2-baked) ----
        const int i = (bid - 8192) * 256 + t;  // 16*2048
        if (i == 0) counter[0] = 0u;           // work-stealing counter for attn
        const int h = i >> 11, d = i & 2047;
        const float vv = vp[h], ww = wp[h];
        tab[i] = (1.f + expf(vv)) / (1.f + expf(vv - ww * (float)d)) *
                 (0.125f * 1.44269504088896340736f);
    }
}

// ---------------- 8-phase-style 256x256 QKV GEMM v2 (conflict-free units) ----------------
// C = A[4096][1024] @ Bt[3072][1024]^T.  512 thr = 8 waves (2M x 4N); per-wave 128x64.
// LDS 128KB dynamic: per operand 2 dbuf x 2 M-HALF units, unit=[128][64] bf16 (16KB) —
// row stride 128B + chunk^(row&7): byte-identical bank pattern to the proven gemm128
// (2-way max = free).  R12's [256][32] units (64B stride, 4-way conflicts) were the
// regression.  Per K-tile: 4 phases (mh x ks), each {8 ds_read_b128 -> barrier ->
// lgkm0 -> setprio + 16 MFMA -> barrier}; ALL 8 next-tile GL2LDS front-loaded in
// phase 0 (~3 phases cover); single vmcnt(0) at phase-3 end (latency already hidden).
// Hazards: stage(kt+1)->dbuf^1 issued post tile-(kt-1)'s final barrier, by which all
// dbuf^1 reads (lgkm0'd) completed; reads of dbuf d at tile kt protected by tile
// (kt-1) ph3's WAITV(0)+SBAR.  XCD-chunked bid swizzle (192 = 8x24, bijective):
// the 12 n-tiles sharing an A-panel land on one XCD's L2.
// Epilogue verbatim from R12 (correctness-verified).
__global__ __launch_bounds__(512, 2) void gemm256(const u16* __restrict__ A,
                                                  const u16* __restrict__ Bt,
                                                  u16* __restrict__ Cb,
                                                  u16* __restrict__ Vt) {
    extern __shared__ u16 sm[];  // [A:0|B:4][dbuf][half][128][64] u16 = 128 KB
    const int t = threadIdx.x, lane = t & 63, w = t >> 6;  // 8 waves
    const int l15 = lane & 15, quad = lane >> 4;
    const int wr = w >> 2, wc = w & 3;
    const int bid0 = blockIdx.y * 12 + blockIdx.x;
    const int bid = (bid0 & 7) * 24 + (bid0 >> 3);  // XCD chunking, 192 = 8*24
    const int bx = bid % 12, by = bid / 12;
    const int m0 = by << 8, n0 = bx << 8;
    const int srow8 = lane >> 3, schunk = lane & 7;

    f32x4 acc[8][4];
#pragma unroll
    for (int i = 0; i < 8; ++i)
#pragma unroll
        for (int j = 0; j < 4; ++j) acc[i][j] = (f32x4){0.f, 0.f, 0.f, 0.f};

    // stage one unit (operand O, dbuf d, M-half hh, K-tile kt): 2 GL2LDS/thread
    auto stageu = [&](int O, int d, int hh, int kt) {
        const u16* src = O ? Bt : A;
        const int g0 = (O ? n0 : m0) + hh * 128;
        u16* base = &sm[(O * 4 + d * 2 + hh) * 8192];
        const int k0 = kt << 6;
#pragma unroll
        for (int j = 0; j < 2; ++j) {
            const int rl = (w * 2 + j) * 8 + srow8;   // row in unit 0..127
            const int g = schunk ^ (rl & 7);          // inverse swizzle on source
            GL2LDS(src + (size_t)(g0 + rl) * 1024 + k0 + g * 8,
                   base + (w * 2 + j) * 512);
        }
    };
    auto stage_tile = [&](int kt) {
        const int d = kt & 1;
        stageu(0, d, 0, kt); stageu(0, d, 1, kt);
        stageu(1, d, 0, kt); stageu(1, d, 1, kt);
    };

    // one phase: quadrant (mh, ks) of tile in dbuf d
    auto phase = [&](int d, int mh, int ks, bool dostage, int kstage, bool dowait) {
        const u16* Au = &sm[(d * 2 + wr) * 8192];
        const u16* Bu = &sm[(4 + d * 2 + (wc >> 1)) * 8192];
        const int p = (ks << 2) | quad;
        bf16x8 af[4], bf[4];
#pragma unroll
        for (int mm = 0; mm < 4; ++mm) {
            const int rl = mh * 64 + mm * 16 + l15;
            af[mm] = *(const bf16x8*)&Au[rl * 64 + ((p ^ (l15 & 7)) << 3)];
        }
#pragma unroll
        for (int nn = 0; nn < 4; ++nn) {
            const int rl = (wc & 1) * 64 + nn * 16 + l15;
            bf[nn] = *(const bf16x8*)&Bu[rl * 64 + ((p ^ (l15 & 7)) << 3)];
        }
        if (dostage) stage_tile(kstage);
        SBAR;
        WAITLGKM0;
        __builtin_amdgcn_s_setprio(1);
#pragma unroll
        for (int mm = 0; mm < 4; ++mm)
#pragma unroll
            for (int nn = 0; nn < 4; ++nn)
                acc[mh * 4 + mm][nn] = __builtin_amdgcn_mfma_f32_16x16x32_bf16(
                    af[mm], bf[nn], acc[mh * 4 + mm][nn], 0, 0, 0);
        __builtin_amdgcn_s_setprio(0);
        if (dowait) WAITV(0);
        SBAR;
    };

    // prologue: tile 0 into dbuf0
    stage_tile(0);
    WAITV(0);
    SBAR;

    for (int kt = 0; kt < 16; ++kt) {
        const int d = kt & 1;
        const bool nl = (kt < 15);
        phase(d, 0, 0, nl, kt + 1, false);  // ph0: stage ALL of next tile
        phase(d, 0, 1, false, 0, false);
        phase(d, 1, 0, false, 0, false);
        phase(d, 1, 1, false, 0, nl);       // ph3: land next tile (covered ~3 phases)
    }

    // epilogue (verbatim from R12, correctness-verified): col=lane&15, row=quad*4+r
    const int cb0 = n0 + wc * 64;
#pragma unroll
    for (int am = 0; am < 8; ++am) {
#pragma unroll
        for (int nn = 0; nn < 4; ++nn) {
            const int col = cb0 + nn * 16 + l15;
            if (n0 < 2048) {  // Q|K: row-major bf16 [M][2048]
                const int row = m0 + wr * 128 + am * 16 + (quad << 2);
#pragma unroll
                for (int r = 0; r < 4; ++r)
                    Cb[(size_t)(row + r) * 2048 + col] = f2bf(acc[am][nn][r]);
            } else {  // V: permuted V^T store (64-row window, proven pos formula)
                const int mm = am & 3, mh = am >> 2;
                const int win = m0 + wr * 128 + mh * 64;
                const int pos = (((mm >> 1) * 4 + quad) << 3) + ((mm & 1) << 2);
                uint2 o;
                o.x = cvtpk(acc[am][nn][0], acc[am][nn][1]);
                o.y = cvtpk(acc[am][nn][2], acc[am][nn][3]);
                *(uint2*)(Vt + (size_t)(col - 2048) * 4096 + win + pos) = o;
            }
        }
    }
}

// ---------------- m97-style bf16 MFMA GEMM (out-proj): 128x64 tile, MODE0 ----------------
template <int MODE, int BN>
__global__ __launch_bounds__(256, 3) void gemm128(const u16* __restrict__ A,
                                                  const u16* __restrict__ Bt,
                                                  float* __restrict__ C,
                                                  const float* __restrict__ bias,
                                                  int M, int N, int K) {
    constexpr int NBW = BN / 32;
    __shared__ __align__(16) u16 As[8192];
    __shared__ __align__(16) u16 Bs[BN * 64];
    const int t = threadIdx.x, lane = t & 63, wv = t >> 6;
    const int l15 = lane & 15, quad = lane >> 4;
    const int m0 = blockIdx.y << 7, n0 = blockIdx.x * BN;
    const int wm = (wv & 1) << 6, wn = (wv >> 1) * (BN / 2);

    f32x4 acc[4][NBW];
#pragma unroll
    for (int i = 0; i < 4; ++i)
#pragma unroll
        for (int j = 0; j < NBW; ++j) acc[i][j] = (f32x4){0.f, 0.f, 0.f, 0.f};

    const int lrow = lane >> 3, lchunk = lane & 7;
    for (int k0 = 0; k0 < K; k0 += 64) {
#pragma unroll
        for (int c = 0; c < 4; ++c) {
            const int r0 = wv * 32 + c * 8;
            const int row = r0 + lrow;
            const int g = lchunk ^ (row & 7);
            GL2LDS(A + (size_t)(m0 + row) * K + k0 + g * 8, &As[r0 * 64]);
        }
#pragma unroll
        for (int c = 0; c < BN / 32; ++c) {
            const int r0 = wv * (BN / 4) + c * 8;
            const int row = r0 + lrow;
            const int g = lchunk ^ (row & 7);
            GL2LDS(Bt + (size_t)(n0 + row) * K + k0 + g * 8, &Bs[r0 * 64]);
        }
        __syncthreads();
#pragma unroll
        for (int ks = 0; ks < 2; ++ks) {
            const int p = ((ks << 2) | quad) ^ (l15 & 7);
            bf16x8 af[4], bfr[NBW];
#pragma unroll
            for (int i = 0; i < 4; ++i)
                af[i] = *(const bf16x8*)&As[(wm + i * 16 + l15) * 64 + p * 8];
#pragma unroll
            for (int j = 0; j < NBW; ++j)
                bfr[j] = *(const bf16x8*)&Bs[(wn + j * 16 + l15) * 64 + p * 8];
#pragma unroll
            for (int mb = 0; mb < 4; ++mb)
#pragma unroll
                for (int nb = 0; nb < NBW; ++nb)
                    acc[mb][nb] = __builtin_amdgcn_mfma_f32_16x16x32_bf16(af[mb], bfr[nb],
                                                                          acc[mb][nb], 0, 0, 0);
        }
        __syncthreads();
    }
    const int rb = m0 + wm + (quad << 2);
    const int cbase = n0 + wn + l15;
#pragma unroll
    for (int mb = 0; mb < 4; ++mb)
#pragma unroll
        for (int nb = 0; nb < NBW; ++nb) {
            const int col = cbase + nb * 16;
#pragma unroll
            for (int r = 0; r < 4; ++r) {
                const int row = rb + mb * 16 + r;
                C[(size_t)row * N + col] = acc[mb][nb][r] + bias[col];
            }
        }
}

// ---------------- MFMA flash attention v13 (R10 best): counted-vmcnt deep pipeline ----
__global__ __launch_bounds__(256, 3) void attn_kernel(const u16* __restrict__ qkb,
                                                      const u16* __restrict__ vtb,
                                                      const float* __restrict__ rtab,
                                                      u16* __restrict__ ctxb,
                                                      u32* __restrict__ counter) {
    __shared__ __align__(16) u16 Kt[3][4096];   // [kseq][d] swizzled, 8KB x3
    __shared__ __align__(16) u16 Vt2[2][4096];  // [d][kseq-permuted] swizzled, 8KB x2
    __shared__ __align__(16) float rall[2048];  // R_hat*log2e/8 row for this head
    __shared__ int jobS;

    const int t = threadIdx.x, lane = t & 63, wv = t >> 6;
    const int l15 = lane & 15, quad = lane >> 4;
    const int lrow = lane >> 3, lchunk = lane & 7;
    const int half0 = (wv & 1) * 32;

    for (;;) {
        if (t == 0) jobS = (int)atomicAdd(counter, 1u);
        __syncthreads();
        const int job = jobS;
        if (job >= 1024) break;
        const int qt = 31 - (job >> 5);
        const int bh = job & 31;
        const int b = bh >> 4, h = bh & 15;
        const int q0 = qt << 6;

        {
            const float4* src = (const float4*)(rtab + (h << 11));
            const int nf = (q0 + 64) >> 2;
            for (int i = t; i < nf; i += 256) ((float4*)rall)[i] = src[i];
        }

        bf16x8 qb[2];
        {
            const u16* qrow = qkb + (size_t)(b * 2048 + q0 + (wv << 4) + l15) * 2048 +
                              (h << 6) + quad * 8;
            qb[0] = *(const bf16x8*)(qrow);
            qb[1] = *(const bf16x8*)(qrow + 32);
        }

        auto stage_k = [&](int ktile, int kb) {
#pragma unroll
            for (int c = 0; c < 4; ++c) {
                const int r0 = half0 + c * 8;
                const int row = r0 + lrow;
                const int g = lchunk ^ (row & 7);
                GL2LDS(qkb + (size_t)(b * 2048 + (ktile << 6) + row) * 2048 + 1024 +
                           (h << 6) + g * 8,
                       &Kt[kb][r0 * 64]);
            }
        };
        auto stage_v = [&](int ktile, int vb) {
#pragma unroll
            for (int c = 0; c < 4; ++c) {
                const int r0 = half0 + c * 8;
                const int row = r0 + lrow;
                const int g = lchunk ^ (row & 7);
                GL2LDS(vtb + (size_t)((h << 6) + row) * 4096 + b * 2048 + (ktile << 6) +
                           g * 8,
                       &Vt2[vb][r0 * 64]);
            }
        };

        f32x4 cacc[4];
#pragma unroll
        for (int i = 0; i < 4; ++i) cacc[i] = (f32x4){0.f, 0.f, 0.f, 0.f};
        f32x4 lacc4 = (f32x4){0.f, 0.f, 0.f, 0.f};

        if (wv < 2) {
            stage_k(0, 0);
            if (qt >= 1) stage_k(1, 1);
        } else {
            stage_v(0, 0);
        }
        WAITLGKM0;  // publish rall fill at b1

        for (int kt = 0; kt <= qt; ++kt) {
            const int kb = kt % 3, vb = kt & 1;
            if (wv < 2) {
                if (kt < qt) WAITV(4);
                else         WAITV(0);
            }
            SBAR;  // b1: Kt[kb] ready
            if (wv < 2) {
                if (kt + 2 <= qt) stage_k(kt + 2, (kt + 2) % 3);
            } else {
                if (kt + 1 <= qt) stage_v(kt + 1, (kt + 1) & 1);
            }

            f32x4 sacc[4];
#pragma unroll
            for (int i = 0; i < 4; ++i) sacc[i] = (f32x4){0.f, 0.f, 0.f, 0.f};
            __builtin_amdgcn_s_setprio(1);
#pragma unroll
            for (int ks = 0; ks < 2; ++ks) {
                const int p = ((ks << 2) | quad) ^ (l15 & 7);
#pragma unroll
                for (int mb = 0; mb < 4; ++mb) {
                    bf16x8 ka = *(const bf16x8*)&Kt[kb][(mb * 16 + l15) * 64 + p * 8];
                    sacc[mb] = __builtin_amdgcn_mfma_f32_16x16x32_bf16(ka, qb[ks],
                                                                       sacc[mb], 0, 0, 0);
                }
            }
            __builtin_amdgcn_s_setprio(0);

            const int D0 = q0 - (kt << 6) + (wv << 4) + l15;
            u32 pk[4][2];
            if (kt < qt) {
#pragma unroll
                for (int mb = 0; mb < 4; ++mb) {
                    float pe[4];
#pragma unroll
                    for (int r = 0; r < 4; ++r) {
                        const int dist = D0 - (mb * 16 + (quad << 2) + r);
                        pe[r] = exp2f(fmaxf(sacc[mb][r], 0.f) * rall[dist]);
                        lacc4[r] += pe[r];
                    }
                    pk[mb][0] = cvtpk(pe[0], pe[1]);
                    pk[mb][1] = cvtpk(pe[2], pe[3]);
                }
            } else {
#pragma unroll
                for (int mb = 0; mb < 4; ++mb) {
                    float pe[4];
#pragma unroll
                    for (int r = 0; r < 4; ++r) {
                        const int dist = D0 - (mb * 16 + (quad << 2) + r);
                        const int di = dist < 0 ? 0 : dist;
                        float p0 = exp2f(fmaxf(sacc[mb][r], 0.f) * rall[di]);
                        pe[r] = (dist < 0) ? 0.f : p0;
                        lacc4[r] += pe[r];
                    }
                    pk[mb][0] = cvtpk(pe[0], pe[1]);
                    pk[mb][1] = cvtpk(pe[2], pe[3]);
                }
            }

            if (wv >= 2) {
                if (kt < qt) WAITV(4);
                else         WAITV(0);
            }
            SBAR;  // b2: Vt2[vb] ready

            __builtin_amdgcn_s_setprio(1);
#pragma unroll
            for (int ks = 0; ks < 2; ++ks) {
                int4 pv = {(int)pk[2 * ks][0], (int)pk[2 * ks][1],
                           (int)pk[2 * ks + 1][0], (int)pk[2 * ks + 1][1]};
                bf16x8 pb = *(bf16x8*)&pv;
                const int g = (4 * ks + quad) ^ (l15 & 7);
#pragma unroll
                for (int db = 0; db < 4; ++db) {
                    bf16x8 vf = *(const bf16x8*)&Vt2[vb][(db * 16 + l15) * 64 + g * 8];
                    cacc[db] = __builtin_amdgcn_mfma_f32_16x16x32_bf16(vf, pb,
                                                                       cacc[db], 0, 0, 0);
                }
            }
            __builtin_amdgcn_s_setprio(0);
        }

        float lt = (lacc4[0] + lacc4[1]) + (lacc4[2] + lacc4[3]);
        lt += __shfl_xor(lt, 16, 64);
        lt += __shfl_xor(lt, 32, 64);
        const float inv = 1.f / lt;
        u16* op = ctxb + (size_t)(b * 2048 + q0 + (wv << 4) + l15) * 1024 +
                  (h << 6) + (quad << 2);
#pragma unroll
        for (int db = 0; db < 4; ++db) {
            uint2 o;
            o.x = cvtpk(cacc[db][0] * inv, cacc[db][1] * inv);
            o.y = cvtpk(cacc[db][2] * inv, cacc[db][3] * inv);
            *(uint2*)(op + db * 16) = o;
        }
    }
}

extern "C" void kernel_launch(void* const* d_in, const int* in_sizes, int n_in,
                              void* d_out, int out_size, void* d_ws, size_t ws_size,
                              hipStream_t stream) {
    const float* x  = (const float*)d_in[0];
    const float* Wq = (const float*)d_in[1];
    const float* Wk = (const float*)d_in[2];
    const float* Wv = (const float*)d_in[3];
    const float* Wo = (const float*)d_in[4];
    const float* bo = (const float*)d_in[5];
    const float* w  = (const float*)d_in[6];
    const float* v  = (const float*)d_in[7];
    float* out = (float*)d_out;

    char* w8 = (char*)d_ws;
    u16*  xb   = (u16*)(w8);                     //  8 MB : x bf16 [4096][1024]
    u16*  Wcat = (u16*)(w8 + (8u << 20));        //  6 MB : (Wq|Wk|Wv)^T bf16 [3072][1024]
    u16*  Wot  = (u16*)(w8 + (14u << 20));       //  2 MB : Wo^T bf16 [1024][1024]
    u16*  qkb  = (u16*)(w8 + (16u << 20));       // 16 MB : Q|K bf16 [4096][2048]
    u16*  vtb  = (u16*)(w8 + (32u << 20));       //  8 MB : V^T bf16 [1024][4096] (permuted)
    u16*  ctxb = (u16*)(w8 + (40u << 20));       //  8 MB : ctx bf16 [4096][1024]
    float* rtab = (float*)(w8 + (48u << 20));    // 128 KB: R_hat*log2e/8 [16][2048]
    u32*  counter = (u32*)(w8 + (48u << 20) + (1u << 17));  // 4 B : job counter

    static bool attrSet = false;
    if (!attrSet) {
        hipFuncSetAttribute(reinterpret_cast<const void*>(gemm256),
                            hipFuncAttributeMaxDynamicSharedMemorySize, 131072);
        attrSet = true;
    }

    // fused prep: cast (4096 blk) | weight transpose (4096 blk) | rtab+counter (128 blk)
    prep_kernel<<<8320, 256, 0, stream>>>(x, Wq, Wk, Wv, Wo, w, v, xb, Wcat, Wot, rtab,
                                          counter);
    // QKV fused projection, 256x256 4-phase v2 -> qkb (Q|K) + vtb (V^T permuted)
    gemm256<<<dim3(12, 16), 512, 131072, stream>>>(xb, Wcat, qkb, vtb);
    // MFMA flash attention: 768 persistent blocks (3/CU), work-stealing
    attn_kernel<<<768, 256, 0, stream>>>(qkb, vtb, rtab, ctxb, counter);
    // output projection + bias (fp32 out)   [M=4096, N=1024, K=1024], 128x64 tiles
    gemm128<0, 64><<<dim3(16, 32), 256, 0, stream>>>(ctxb, Wot, out, bo, 4096, 1024, 1024);
}

// Round 14
// 188.982 us; speedup vs baseline: 1.0387x; 1.0303x over previous
//
#include <hip/hip_runtime.h>

typedef unsigned short u16;
typedef unsigned int u32;
typedef __attribute__((ext_vector_type(8))) short bf16x8;
typedef __attribute__((ext_vector_type(4))) float f32x4;

__device__ __forceinline__ u16 f2bf(float f) {
    u32 u = __float_as_uint(f);
    u += 0x7fffu + ((u >> 16) & 1u);
    return (u16)(u >> 16);
}

// pack two f32 -> one u32 of two bf16 (RNE), 1 VALU inst
__device__ __forceinline__ u32 cvtpk(float lo, float hi) {
    u32 r;
    asm("v_cvt_pk_bf16_f32 %0, %1, %2" : "=v"(r) : "v"(lo), "v"(hi));
    return r;
}

// async global->LDS DMA, 16B per lane, LDS dest = wave-uniform base + lane*16
#define GL2LDS(gp, lp)                                                                 \
    __builtin_amdgcn_global_load_lds((const __attribute__((address_space(1))) u32*)(const void*)(gp), \
                                     (__attribute__((address_space(3))) u32*)(void*)(lp), 16, 0, 0)

#define SBAR                                                                           \
    do {                                                                               \
        __builtin_amdgcn_sched_barrier(0);                                             \
        __builtin_amdgcn_s_barrier();                                                  \
        __builtin_amdgcn_sched_barrier(0);                                             \
    } while (0)
#define WAITV(N)                                                                       \
    do {                                                                               \
        asm volatile("s_waitcnt vmcnt(" #N ")" ::: "memory");                          \
        __builtin_amdgcn_sched_barrier(0);                                             \
    } while (0)
#define WAITLGKM0                                                                      \
    do {                                                                               \
        asm volatile("s_waitcnt lgkmcnt(0)" ::: "memory");                             \
        __builtin_amdgcn_sched_barrier(0);                                             \
    } while (0)

// ------------- fused prep: cast x (bid<4096) | transpose W (bid<8192) | rtab -------------
__global__ __launch_bounds__(256) void prep_kernel(const float* __restrict__ x,
                                                   const float* __restrict__ Wq,
                                                   const float* __restrict__ Wk,
                                                   const float* __restrict__ Wv,
                                                   const float* __restrict__ Wo,
                                                   const float* __restrict__ wp,
                                                   const float* __restrict__ vp,
                                                   u16* __restrict__ xb,
                                                   u16* __restrict__ Wcat,
                                                   u16* __restrict__ Wot,
                                                   float* __restrict__ tab,
                                                   u32* __restrict__ counter) {
    __shared__ float tl[32][33];
    const int bid = blockIdx.x, t = threadIdx.x;
    if (bid < 4096) {  // ---- cast x fp32 -> bf16, float4/thread ----
        const int i = bid * 256 + t;
        float4 val = ((const float4*)x)[i];
        uint2 o;
        o.x = cvtpk(val.x, val.y);
        o.y = cvtpk(val.z, val.w);
        ((uint2*)xb)[i] = o;
    } else if (bid < 8192) {  // ---- transpose+cast one 32x32 tile of Wq/Wk/Wv/Wo ----
        const int tid = bid - 4096;
        const int zi = tid >> 10, rem = tid & 1023;
        const int kt = (rem >> 5) * 32, nt = (rem & 31) * 32;
        const float* src = (zi == 0) ? Wq : (zi == 1) ? Wk : (zi == 2) ? Wv : Wo;
        u16* dst = (zi < 3) ? (Wcat + zi * 1048576) : Wot;
        const int tx = t & 31, ty = t >> 5;
#pragma unroll
        for (int j = 0; j < 4; ++j)
            tl[ty + j * 8][tx] = src[(kt + ty + j * 8) * 1024 + nt + tx];
        __syncthreads();
#pragma unroll
        for (int j = 0; j < 4; ++j)
            dst[(nt + ty + j * 8) * 1024 + kt + tx] = f2bf(tl[tx][ty + j * 8]);
    } else {  // ---- R_hat table: (1+e^v)/(1+e^(v-w*d))/8 * log2e (exp2-baked) ----
        const int i = (bid - 8192) * 256 + t;  // 16*2048
        if (i == 0) counter[0] = 0u;           // work-stealing counter for attn
        const int h = i >> 11, d = i & 2047;
        const float vv = vp[h], ww = wp[h];
        tab[i] = (1.f + expf(vv)) / (1.f + expf(vv - ww * (float)d)) *
                 (0.125f * 1.44269504088896340736f);
    }
}

// ---------------- m97-style bf16 MFMA GEMM: 128xBN tile, BK=64, global_load_lds ------
// C = A[M][K] @ Bt[N][K]^T.  LDS tiles unpadded, XOR-swizzled (chunk ^= row&7).
// MODE 0: fp32 out + bias.
// MODE 1: col<2048 -> Cb bf16 [M][2048] (Q|K); col>=2048 -> Vt bf16 [1024][4096] (V^T,
//         with seq order inside each 64-block PERMUTED so attn PV A-frags are one 16B:
//         seq = 32a+16b+4c+d  ->  pos = (4a+c)*8 + 4b + d).  [verified R2: conflicts 0]
// NOTE (R12/R13): the 256^2 8-phase template REGRESSED here — grid 192 < 256 CUs at
// this shape (M=4096,N=3072) leaves 64 CUs idle and kills cross-block overlap.  This
// 128-tile 3-blocks/CU structure is the verified best QKV on this shape.
template <int MODE, int BN>
__global__ __launch_bounds__(256, 3) void gemm128(const u16* __restrict__ A,
                                                  const u16* __restrict__ Bt,
                                                  float* __restrict__ C,
                                                  const float* __restrict__ bias,
                                                  u16* __restrict__ Cb,
                                                  u16* __restrict__ Vt,
                                                  int M, int N, int K) {
    constexpr int NBW = BN / 32;  // 16-wide n-blocks per wave
    __shared__ __align__(16) u16 As[8192];      // 128 rows x 64
    __shared__ __align__(16) u16 Bs[BN * 64];   // BN rows x 64
    const int t = threadIdx.x, lane = t & 63, wv = t >> 6;
    const int l15 = lane & 15, quad = lane >> 4;
    const int m0 = blockIdx.y << 7, n0 = blockIdx.x * BN;
    const int wm = (wv & 1) << 6, wn = (wv >> 1) * (BN / 2);

    f32x4 acc[4][NBW];
#pragma unroll
    for (int i = 0; i < 4; ++i)
#pragma unroll
        for (int j = 0; j < NBW; ++j) acc[i][j] = (f32x4){0.f, 0.f, 0.f, 0.f};

    const int lrow = lane >> 3, lchunk = lane & 7;
    for (int k0 = 0; k0 < K; k0 += 64) {
#pragma unroll
        for (int c = 0; c < 4; ++c) {  // A: 128 rows
            const int r0 = wv * 32 + c * 8;
            const int row = r0 + lrow;
            const int g = lchunk ^ (row & 7);
            GL2LDS(A + (size_t)(m0 + row) * K + k0 + g * 8, &As[r0 * 64]);
        }
#pragma unroll
        for (int c = 0; c < BN / 32; ++c) {  // B: BN rows
            const int r0 = wv * (BN / 4) + c * 8;
            const int row = r0 + lrow;
            const int g = lchunk ^ (row & 7);
            GL2LDS(Bt + (size_t)(n0 + row) * K + k0 + g * 8, &Bs[r0 * 64]);
        }
        __syncthreads();  // drains global_load_lds (vmcnt) + protects prior reads
#pragma unroll
        for (int ks = 0; ks < 2; ++ks) {
            const int p = ((ks << 2) | quad) ^ (l15 & 7);
            bf16x8 af[4], bfr[NBW];
#pragma unroll
            for (int i = 0; i < 4; ++i)
                af[i] = *(const bf16x8*)&As[(wm + i * 16 + l15) * 64 + p * 8];
#pragma unroll
            for (int j = 0; j < NBW; ++j)
                bfr[j] = *(const bf16x8*)&Bs[(wn + j * 16 + l15) * 64 + p * 8];
#pragma unroll
            for (int mb = 0; mb < 4; ++mb)
#pragma unroll
                for (int nb = 0; nb < NBW; ++nb)
                    acc[mb][nb] = __builtin_amdgcn_mfma_f32_16x16x32_bf16(af[mb], bfr[nb],
                                                                          acc[mb][nb], 0, 0, 0);
        }
        __syncthreads();  // protect LDS before next stage overwrites
    }
    // epilogue: C/D layout col=lane&15, row=(lane>>4)*4+reg
    const int rb = m0 + wm + (quad << 2);
    const int cbase = n0 + wn + l15;
#pragma unroll
    for (int mb = 0; mb < 4; ++mb)
#pragma unroll
        for (int nb = 0; nb < NBW; ++nb) {
            const int col = cbase + nb * 16;
            if (MODE == 0) {
#pragma unroll
                for (int r = 0; r < 4; ++r) {
                    const int row = rb + mb * 16 + r;
                    C[(size_t)row * N + col] = acc[mb][nb][r] + bias[col];
                }
            } else if (col < 2048) {  // Q|K: row-major bf16 [M][2048]
#pragma unroll
                for (int r = 0; r < 4; ++r) {
                    const int row = rb + mb * 16 + r;
                    Cb[(size_t)row * 2048 + col] = f2bf(acc[mb][nb][r]);
                }
            } else {  // V: permuted V^T store; lane's 4 seq rows are 4 consecutive pos
                const int pos = (((mb >> 1) * 4 + quad) << 3) + ((mb & 1) << 2);
                uint2 o;
                o.x = cvtpk(acc[mb][nb][0], acc[mb][nb][1]);
                o.y = cvtpk(acc[mb][nb][2], acc[mb][nb][3]);
                *(uint2*)(Vt + (size_t)(col - 2048) * 4096 + (m0 + wm) + pos) = o;
            }
        }
}

// ---------------- MFMA flash attention v13 (champion, R10: 184.3us): counted-vmcnt ----
// S^T = K@Q^T (softmax denom is per-lane scalar, P stays in registers), PV = V^T@P^T
// with B-frag == lane's own packs.  Sync: raw s_barrier + counted vmcnt (T4).
// K: 3 buffers depth-2 (K-waves vmcnt(4) pre-b1); V: 2 buffers depth-1 landed at b2
// (V-waves vmcnt(4) pre-b2).  In-order vmem retirement makes counts exact; tails use
// vmcnt(0).  3 blocks/CU (LDS 48.1KB); rall in LDS lgkm domain (R2 lesson); no
// launch_bounds tightening (R4 spill lesson); 4-wave blocks (R6 overlap lesson).
__global__ __launch_bounds__(256, 3) void attn_kernel(const u16* __restrict__ qkb,
                                                      const u16* __restrict__ vtb,
                                                      const float* __restrict__ rtab,
                                                      u16* __restrict__ ctxb,
                                                      u32* __restrict__ counter) {
    __shared__ __align__(16) u16 Kt[3][4096];   // [kseq][d] swizzled, 8KB x3
    __shared__ __align__(16) u16 Vt2[2][4096];  // [d][kseq-permuted] swizzled, 8KB x2
    __shared__ __align__(16) float rall[2048];  // R_hat*log2e/8 row for this head
    __shared__ int jobS;

    const int t = threadIdx.x, lane = t & 63, wv = t >> 6;
    const int l15 = lane & 15, quad = lane >> 4;
    const int lrow = lane >> 3, lchunk = lane & 7;
    const int half0 = (wv & 1) * 32;

    for (;;) {
        if (t == 0) jobS = (int)atomicAdd(counter, 1u);
        __syncthreads();       // jobS visible; full fence between jobs
        const int job = jobS;
        if (job >= 1024) break;
        const int qt = 31 - (job >> 5);       // longest jobs first
        const int bh = job & 31;
        const int b = bh >> 4, h = bh & 15;
        const int q0 = qt << 6;

        // rall fill, vectorized f32x4 (q0+64 is a multiple of 64 -> exact)
        {
            const float4* src = (const float4*)(rtab + (h << 11));
            const int nf = (q0 + 64) >> 2;
            for (int i = t; i < nf; i += 256) ((float4*)rall)[i] = src[i];
        }

        // Q as B-operand fragments for S^T: lane n=l15 -> q = q0+wv*16+l15, k=d
        bf16x8 qb[2];
        {
            const u16* qrow = qkb + (size_t)(b * 2048 + q0 + (wv << 4) + l15) * 2048 +
                              (h << 6) + quad * 8;
            qb[0] = *(const bf16x8*)(qrow);
            qb[1] = *(const bf16x8*)(qrow + 32);
        }

        // staging lambdas: waves 0,1 own K rows half0..half0+31; waves 2,3 own V rows
        auto stage_k = [&](int ktile, int kb) {
#pragma unroll
            for (int c = 0; c < 4; ++c) {
                const int r0 = half0 + c * 8;
                const int row = r0 + lrow;
                const int g = lchunk ^ (row & 7);
                GL2LDS(qkb + (size_t)(b * 2048 + (ktile << 6) + row) * 2048 + 1024 +
                           (h << 6) + g * 8,
                       &Kt[kb][r0 * 64]);
            }
        };
        auto stage_v = [&](int ktile, int vb) {
#pragma unroll
            for (int c = 0; c < 4; ++c) {
                const int r0 = half0 + c * 8;
                const int row = r0 + lrow;
                const int g = lchunk ^ (row & 7);
                GL2LDS(vtb + (size_t)((h << 6) + row) * 4096 + b * 2048 + (ktile << 6) +
                           g * 8,
                       &Vt2[vb][r0 * 64]);
            }
        };

        f32x4 cacc[4];   // ctx^T accum: db d-blocks, lane holds (d=quad*4+r, q=l15)
#pragma unroll
        for (int i = 0; i < 4; ++i) cacc[i] = (f32x4){0.f, 0.f, 0.f, 0.f};
        f32x4 lacc4 = (f32x4){0.f, 0.f, 0.f, 0.f};  // 4-chain softmax denom partials

        // prologue: K depth-2 (kt=0,1), V depth-1 (kt=0)
        if (wv < 2) {
            stage_k(0, 0);
            if (qt >= 1) stage_k(1, 1);
        } else {
            stage_v(0, 0);
        }
        WAITLGKM0;  // publish rall fill at b1

        for (int kt = 0; kt <= qt; ++kt) {
            const int kb = kt % 3, vb = kt & 1;
            // ---- pre-b1: K-waves retire K kt (leave K kt+1 in flight) ----
            if (wv < 2) {
                if (kt < qt) WAITV(4);
                else         WAITV(0);
            }
            SBAR;  // b1: Kt[kb] ready for all waves
            // ---- issue next tiles (targets last read at iter kt-1: safe post-b1) ----
            if (wv < 2) {
                if (kt + 2 <= qt) stage_k(kt + 2, (kt + 2) % 3);
            } else {
                if (kt + 1 <= qt) stage_v(kt + 1, (kt + 1) & 1);
            }

            // ---- S^T = K @ Q^T : 8 MFMA, A=K from LDS ----
            f32x4 sacc[4];
#pragma unroll
            for (int i = 0; i < 4; ++i) sacc[i] = (f32x4){0.f, 0.f, 0.f, 0.f};
            __builtin_amdgcn_s_setprio(1);
#pragma unroll
            for (int ks = 0; ks < 2; ++ks) {
                const int p = ((ks << 2) | quad) ^ (l15 & 7);
#pragma unroll
                for (int mb = 0; mb < 4; ++mb) {
                    bf16x8 ka = *(const bf16x8*)&Kt[kb][(mb * 16 + l15) * 64 + p * 8];
                    sacc[mb] = __builtin_amdgcn_mfma_f32_16x16x32_bf16(ka, qb[ks],
                                                                       sacc[mb], 0, 0, 0);
                }
            }
            __builtin_amdgcn_s_setprio(0);

            // ---- gate + exp2 (fixed m=0), 4-chain l accum, cvt_pk P to bf16 regs ----
            const int D0 = q0 - (kt << 6) + (wv << 4) + l15;
            u32 pk[4][2];
            if (kt < qt) {  // off-diagonal: dist >= 1 guaranteed
#pragma unroll
                for (int mb = 0; mb < 4; ++mb) {
                    float pe[4];
#pragma unroll
                    for (int r = 0; r < 4; ++r) {
                        const int dist = D0 - (mb * 16 + (quad << 2) + r);
                        pe[r] = exp2f(fmaxf(sacc[mb][r], 0.f) * rall[dist]);
                        lacc4[r] += pe[r];
                    }
                    pk[mb][0] = cvtpk(pe[0], pe[1]);
                    pk[mb][1] = cvtpk(pe[2], pe[3]);
                }
            } else {  // diagonal tile: causal mask (dist<0 -> 0)
#pragma unroll
                for (int mb = 0; mb < 4; ++mb) {
                    float pe[4];
#pragma unroll
                    for (int r = 0; r < 4; ++r) {
                        const int dist = D0 - (mb * 16 + (quad << 2) + r);
                        const int di = dist < 0 ? 0 : dist;
                        float p0 = exp2f(fmaxf(sacc[mb][r], 0.f) * rall[di]);
                        pe[r] = (dist < 0) ? 0.f : p0;
                        lacc4[r] += pe[r];
                    }
                    pk[mb][0] = cvtpk(pe[0], pe[1]);
                    pk[mb][1] = cvtpk(pe[2], pe[3]);
                }
            }

            // ---- pre-b2: V-waves retire V kt (leave V kt+1 in flight) ----
            if (wv >= 2) {
                if (kt < qt) WAITV(4);
                else         WAITV(0);
            }
            SBAR;  // b2: Vt2[vb] ready for all waves

            // ---- ctx^T += V^T @ P^T : 8 MFMA, A-frag one b128 (permuted Vt2) ----
            __builtin_amdgcn_s_setprio(1);
#pragma unroll
            for (int ks = 0; ks < 2; ++ks) {
                int4 pv = {(int)pk[2 * ks][0], (int)pk[2 * ks][1],
                           (int)pk[2 * ks + 1][0], (int)pk[2 * ks + 1][1]};
                bf16x8 pb = *(bf16x8*)&pv;
                const int g = (4 * ks + quad) ^ (l15 & 7);
#pragma unroll
                for (int db = 0; db < 4; ++db) {
                    bf16x8 vf = *(const bf16x8*)&Vt2[vb][(db * 16 + l15) * 64 + g * 8];
                    cacc[db] = __builtin_amdgcn_mfma_f32_16x16x32_bf16(vf, pb,
                                                                       cacc[db], 0, 0, 0);
                }
            }
            __builtin_amdgcn_s_setprio(0);
        }

        // ---- epilogue: l = quad-column reduce; normalize; store ctx (8B/store) ----
        float lt = (lacc4[0] + lacc4[1]) + (lacc4[2] + lacc4[3]);
        lt += __shfl_xor(lt, 16, 64);
        lt += __shfl_xor(lt, 32, 64);
        const float inv = 1.f / lt;
        u16* op = ctxb + (size_t)(b * 2048 + q0 + (wv << 4) + l15) * 1024 +
                  (h << 6) + (quad << 2);
#pragma unroll
        for (int db = 0; db < 4; ++db) {
            uint2 o;
            o.x = cvtpk(cacc[db][0] * inv, cacc[db][1] * inv);
            o.y = cvtpk(cacc[db][2] * inv, cacc[db][3] * inv);
            *(uint2*)(op + db * 16) = o;
        }
        // job-top __syncthreads fences these LDS reads before next job's writes
    }
}

extern "C" void kernel_launch(void* const* d_in, const int* in_sizes, int n_in,
                              void* d_out, int out_size, void* d_ws, size_t ws_size,
                              hipStream_t stream) {
    const float* x  = (const float*)d_in[0];
    const float* Wq = (const float*)d_in[1];
    const float* Wk = (const float*)d_in[2];
    const float* Wv = (const float*)d_in[3];
    const float* Wo = (const float*)d_in[4];
    const float* bo = (const float*)d_in[5];
    const float* w  = (const float*)d_in[6];
    const float* v  = (const float*)d_in[7];
    float* out = (float*)d_out;

    char* w8 = (char*)d_ws;
    u16*  xb   = (u16*)(w8);                     //  8 MB : x bf16 [4096][1024]
    u16*  Wcat = (u16*)(w8 + (8u << 20));        //  6 MB : (Wq|Wk|Wv)^T bf16 [3072][1024]
    u16*  Wot  = (u16*)(w8 + (14u << 20));       //  2 MB : Wo^T bf16 [1024][1024]
    u16*  qkb  = (u16*)(w8 + (16u << 20));       // 16 MB : Q|K bf16 [4096][2048]
    u16*  vtb  = (u16*)(w8 + (32u << 20));       //  8 MB : V^T bf16 [1024][4096] (permuted)
    u16*  ctxb = (u16*)(w8 + (40u << 20));       //  8 MB : ctx bf16 [4096][1024]
    float* rtab = (float*)(w8 + (48u << 20));    // 128 KB: R_hat*log2e/8 [16][2048]
    u32*  counter = (u32*)(w8 + (48u << 20) + (1u << 17));  // 4 B : job counter

    // fused prep: cast (4096 blk) | weight transpose (4096 blk) | rtab+counter (128 blk)
    prep_kernel<<<8320, 256, 0, stream>>>(x, Wq, Wk, Wv, Wo, w, v, xb, Wcat, Wot, rtab,
                                          counter);
    // QKV fused projection -> bf16 qkb (Q|K) + vtb (V^T permuted)  [M=4096, N=3072, K=1024]
    gemm128<1, 128><<<dim3(24, 32), 256, 0, stream>>>(xb, Wcat, nullptr, nullptr, qkb, vtb,
                                                      4096, 3072, 1024);
    // MFMA flash attention: 768 persistent blocks (3/CU), work-stealing
    attn_kernel<<<768, 256, 0, stream>>>(qkb, vtb, rtab, ctxb, counter);
    // output projection + bias (fp32 out)   [M=4096, N=1024, K=1024], 128x64 tiles
    gemm128<0, 64><<<dim3(16, 32), 256, 0, stream>>>(ctxb, Wot, out, bo, nullptr, nullptr,
                                                     4096, 1024, 1024);
}